// Round 4
// baseline (473.867 us; speedup 1.0000x reference)
//
#include <hip/hip_runtime.h>
#include <math.h>

#define BS  8192
#define D   1024
#define TPB 256
#define NW  512               // worker tickets; co-resident even at 2 blocks/CU
#define RPW (BS / NW)         // 16 rows of w per worker slice
#define F4T (RPW * D / 4 / TPB)  // 16 float4 per thread per slice

// ctrl[0]=ticket  ctrl[1]=done  ctrl[2]=wnrm(float bits)  ctrl[3]=flag
__global__ __launch_bounds__(TPB) void planar_one(
    const float* __restrict__ z, const float* __restrict__ w,
    const float* __restrict__ u, const float* __restrict__ b,
    float* __restrict__ zout, float* __restrict__ ldout,
    float* __restrict__ partials, unsigned int* __restrict__ ctrl)
{
    const int row = blockIdx.x;
    const int t   = threadIdx.x;
    const size_t base = (size_t)row * D;

    // issue own-row loads first (prefetch; needed by every block)
    const float4 zv = ((const float4*)(z + base))[t];
    const float4 wv = ((const float4*)(w + base))[t];
    const float4 uv = ((const float4*)(u + base))[t];
    const float brow = b[row];

    __shared__ unsigned int s_tick;
    __shared__ int   s_last;
    __shared__ float sred[12];
    __shared__ float s_wnrm;

    if (t == 0)
        s_tick = __hip_atomic_fetch_add(&ctrl[0], 1u, __ATOMIC_RELAXED,
                                        __HIP_MEMORY_SCOPE_AGENT);
    __syncthreads();
    const unsigned int tick = s_tick;   // block-uniform

    if (tick < NW) {
        // ---- worker: global sum of w^2 over slice rows [tick*RPW, +RPW) ----
        const float4* ws4 = (const float4*)(w + (size_t)tick * RPW * D);
        float ps = 0.f;
#pragma unroll
        for (int k = 0; k < F4T; ++k) {
            const float4 v = ws4[t + k * TPB];
            ps += v.x*v.x + v.y*v.y + v.z*v.z + v.w*v.w;
        }
#pragma unroll
        for (int off = 32; off > 0; off >>= 1) ps += __shfl_down(ps, off, 64);
        if ((t & 63) == 0) sred[t >> 6] = ps;
        __syncthreads();
        if (t == 0) {
            const float pt = sred[0] + sred[1] + sred[2] + sred[3];
            __hip_atomic_store(&partials[tick], pt, __ATOMIC_RELAXED,
                               __HIP_MEMORY_SCOPE_AGENT);
            const unsigned int dn =
                __hip_atomic_fetch_add(&ctrl[1], 1u, __ATOMIC_ACQ_REL,
                                       __HIP_MEMORY_SCOPE_AGENT);
            s_last = (dn == NW - 1);
        }
        __syncthreads();
        if (s_last) {
            // deterministic block-parallel sum of the NW partials
            float s = 0.f;
#pragma unroll
            for (int i = 0; i < NW / TPB; ++i)
                s += __hip_atomic_load(&partials[t + i * TPB], __ATOMIC_RELAXED,
                                       __HIP_MEMORY_SCOPE_AGENT);
#pragma unroll
            for (int off = 32; off > 0; off >>= 1) s += __shfl_down(s, off, 64);
            if ((t & 63) == 0) sred[4 + (t >> 6)] = s;
            __syncthreads();
            if (t == 0) {
                const float wn = sqrtf(sred[4] + sred[5] + sred[6] + sred[7]);
                __hip_atomic_store((float*)&ctrl[2], wn, __ATOMIC_RELAXED,
                                   __HIP_MEMORY_SCOPE_AGENT);
                __hip_atomic_store(&ctrl[3], 1u, __ATOMIC_RELEASE,
                                   __HIP_MEMORY_SCOPE_AGENT);
            }
        }
    }

    // ---- row reductions (all blocks): wu, wz, w2 ----
    float wu = wv.x*uv.x + wv.y*uv.y + wv.z*uv.z + wv.w*uv.w;
    float wz = wv.x*zv.x + wv.y*zv.y + wv.z*zv.z + wv.w*zv.w;
    float w2 = wv.x*wv.x + wv.y*wv.y + wv.z*wv.z + wv.w*wv.w;
#pragma unroll
    for (int off = 32; off > 0; off >>= 1) {
        wu += __shfl_down(wu, off, 64);
        wz += __shfl_down(wz, off, 64);
        w2 += __shfl_down(w2, off, 64);
    }
    __syncthreads();   // protect sred reuse (worker phase done with it)
    if ((t & 63) == 0) {
        const int wi = t >> 6;
        sred[wi] = wu; sred[4 + wi] = wz; sred[8 + wi] = w2;
    }
    __syncthreads();
    wu = sred[0] + sred[1] + sred[2] + sred[3];
    wz = sred[4] + sred[5] + sred[6] + sred[7];
    w2 = sred[8] + sred[9] + sred[10] + sred[11];

    // ---- wait for global wnrm ----
    if (t == 0) {
        while (__hip_atomic_load(&ctrl[3], __ATOMIC_ACQUIRE,
                                 __HIP_MEMORY_SCOPE_AGENT) == 0u)
            __builtin_amdgcn_s_sleep(2);
        s_wnrm = __hip_atomic_load((const float*)&ctrl[2], __ATOMIC_RELAXED,
                                   __HIP_MEMORY_SCOPE_AGENT);
    }
    __syncthreads();
    const float wnrm = s_wnrm;

    // ---- finalize ----
    const float inner = wz + brow;
    const float tnh   = tanhf(inner);
    const float sp    = (wu > 0.f) ? (wu + log1pf(expf(-wu))) : log1pf(expf(wu));
    const float coef  = (-1.f + sp - wu) / wnrm;
    const float tc    = tnh * coef;

    float4 o;
    o.x = fmaf(tnh, uv.x, fmaf(tc, wv.x, zv.x));
    o.y = fmaf(tnh, uv.y, fmaf(tc, wv.y, zv.y));
    o.z = fmaf(tnh, uv.z, fmaf(tc, wv.z, zv.z));
    o.w = fmaf(tnh, uv.w, fmaf(tc, wv.w, zv.w));
    ((float4*)(zout + base))[t] = o;

    if (t == 0) {
        const float s      = fmaf(coef, w2, wu);
        const float inner2 = fmaf(tnh, s, inner);
        const float th2    = tanhf(inner2);
        const float hp     = 1.f - th2 * th2;
        ldout[row] = logf(fabsf(fmaf(hp, s, 1.f)));
    }
}

extern "C" void kernel_launch(void* const* d_in, const int* in_sizes, int n_in,
                              void* d_out, int out_size, void* d_ws, size_t ws_size,
                              hipStream_t stream) {
    const float* z = (const float*)d_in[0];
    const float* w = (const float*)d_in[1];
    const float* u = (const float*)d_in[2];
    const float* b = (const float*)d_in[3];

    float* out   = (float*)d_out;
    float* zout  = out;                    // [BS, D]
    float* ldout = out + (size_t)BS * D;   // [BS]

    float*        partials = (float*)d_ws;                 // [NW]
    unsigned int* ctrl     = (unsigned int*)(partials + NW); // [4]

    hipMemsetAsync(ctrl, 0, 4 * sizeof(unsigned int), stream);
    planar_one<<<BS, TPB, 0, stream>>>(z, w, u, b, zout, ldout, partials, ctrl);
}

// Round 6
// 32.076 us; speedup vs baseline: 14.7731x; 14.7731x over previous
//
#include <hip/hip_runtime.h>
#include <math.h>

#define BS 8192
#define D  1024
#define TPB 256
#define NPART 512   // wsum blocks / partial count

typedef float floatx4 __attribute__((ext_vector_type(4)));

// ---------------------------------------------------------------------------
// Kernel 1: block partials of sum(w^2). 512 blocks x 256 threads, each thread
// 16 coalesced float4 (grid-stride). Reads only w (32 MB).
// ---------------------------------------------------------------------------
__global__ __launch_bounds__(TPB) void wsum_kernel(
    const float* __restrict__ w, float* __restrict__ partials)
{
    const int t   = threadIdx.x;
    const int gid = blockIdx.x * TPB + t;
    const float4* w4 = (const float4*)w;
    float s = 0.f;
#pragma unroll
    for (int i = 0; i < (BS * D / 4) / (NPART * TPB); ++i) {
        const float4 v = w4[gid + i * (NPART * TPB)];
        s += v.x*v.x + v.y*v.y + v.z*v.z + v.w*v.w;
    }
#pragma unroll
    for (int off = 32; off > 0; off >>= 1) s += __shfl_down(s, off, 64);
    __shared__ float sm[4];
    if ((t & 63) == 0) sm[t >> 6] = s;
    __syncthreads();
    if (t == 0) partials[blockIdx.x] = sm[0] + sm[1] + sm[2] + sm[3];
}

// ---------------------------------------------------------------------------
// Kernel 2: fused. Every block redundantly reduces the 512 partials (L2-hot,
// 2 loads/thread, deterministic fixed order) -> wnrm, folded into the same
// reduction round as the row sums. Then finalize from registers.
//   wu = sum w*u ; wz = sum w*z ; w2 = sum w*w
//   m = -1 + softplus(wu); coef = (m - wu)/wnrm
//   inner = wz + b; tnh = tanh(inner)
//   z_new = z + tnh*(u + coef*w)                      (non-temporal store)
//   s = wu + coef*w2 ; inner2 = inner + tnh*s         (identity, no re-reduce)
//   log_det = log|1 + (1 - tanh(inner2)^2) * s|
// ---------------------------------------------------------------------------
__global__ __launch_bounds__(TPB) void fused_row_kernel(
    const float* __restrict__ z, const float* __restrict__ w,
    const float* __restrict__ u, const float* __restrict__ b,
    const float* __restrict__ partials,
    float* __restrict__ zout, float* __restrict__ ldout)
{
    const int row = blockIdx.x;
    const int t   = threadIdx.x;
    const size_t base = (size_t)row * D;

    const float4 zv = ((const float4*)(z + base))[t];
    const float4 wv = ((const float4*)(w + base))[t];
    const float4 uv = ((const float4*)(u + base))[t];
    const float gp  = partials[t] + partials[t + TPB];   // 512 partials

    float wu = wv.x*uv.x + wv.y*uv.y + wv.z*uv.z + wv.w*uv.w;
    float wz = wv.x*zv.x + wv.y*zv.y + wv.z*zv.z + wv.w*zv.w;
    float w2 = wv.x*wv.x + wv.y*wv.y + wv.z*wv.z + wv.w*wv.w;
    float gs = gp;

#pragma unroll
    for (int off = 32; off > 0; off >>= 1) {
        wu += __shfl_down(wu, off, 64);
        wz += __shfl_down(wz, off, 64);
        w2 += __shfl_down(w2, off, 64);
        gs += __shfl_down(gs, off, 64);
    }
    __shared__ float sred[16];
    if ((t & 63) == 0) {
        const int wi = t >> 6;
        sred[wi] = wu; sred[4 + wi] = wz; sred[8 + wi] = w2; sred[12 + wi] = gs;
    }
    __syncthreads();
    wu = sred[0] + sred[1] + sred[2] + sred[3];
    wz = sred[4] + sred[5] + sred[6] + sred[7];
    w2 = sred[8] + sred[9] + sred[10] + sred[11];
    const float gw2 = sred[12] + sred[13] + sred[14] + sred[15];

    const float wnrm  = sqrtf(gw2);
    const float inner = wz + b[row];
    const float tnh   = tanhf(inner);
    const float sp    = (wu > 0.f) ? (wu + log1pf(expf(-wu))) : log1pf(expf(wu));
    const float coef  = (-1.f + sp - wu) / wnrm;
    const float tc    = tnh * coef;

    floatx4 o;
    o.x = fmaf(tnh, uv.x, fmaf(tc, wv.x, zv.x));
    o.y = fmaf(tnh, uv.y, fmaf(tc, wv.y, zv.y));
    o.z = fmaf(tnh, uv.z, fmaf(tc, wv.z, zv.z));
    o.w = fmaf(tnh, uv.w, fmaf(tc, wv.w, zv.w));
    __builtin_nontemporal_store(o, (floatx4*)(zout + base) + t);

    if (t == 0) {
        const float s      = fmaf(coef, w2, wu);
        const float inner2 = fmaf(tnh, s, inner);
        const float th2    = tanhf(inner2);
        const float hp     = 1.f - th2 * th2;
        ldout[row] = logf(fabsf(fmaf(hp, s, 1.f)));
    }
}

extern "C" void kernel_launch(void* const* d_in, const int* in_sizes, int n_in,
                              void* d_out, int out_size, void* d_ws, size_t ws_size,
                              hipStream_t stream) {
    const float* z = (const float*)d_in[0];
    const float* w = (const float*)d_in[1];
    const float* u = (const float*)d_in[2];
    const float* b = (const float*)d_in[3];

    float* out   = (float*)d_out;
    float* zout  = out;                    // [BS, D]
    float* ldout = out + (size_t)BS * D;   // [BS]

    float* partials = (float*)d_ws;        // [NPART]

    wsum_kernel<<<NPART, TPB, 0, stream>>>(w, partials);
    fused_row_kernel<<<BS, TPB, 0, stream>>>(z, w, u, b, partials, zout, ldout);
}